// Round 2
// 509.074 us; speedup vs baseline: 1.0302x; 1.0302x over previous
//
#include <hip/hip_runtime.h>

// Problem constants (fixed by setup_inputs) — all tensors fp32 on the wire.
#define C_CH  512
#define R_CH  128
#define BATCH 8
#define HW    16384                 // 128*128
#define HW4   (HW / 4)              // 4096 float4 per plane
#define NPLANE (BATCH * C_CH)       // 4096
#define PPB   4                     // planes per block in fused kernel (same batch)
#define NBLK  (NPLANE / PPB)        // 1024

// Native vector type — __builtin_nontemporal_store rejects HIP_vector_type.
typedef float floatx4 __attribute__((ext_vector_type(4)));

__device__ __forceinline__ float relu6f(float v) {
    return fminf(fmaxf(v, 0.0f), 6.0f);
}

// ---- Kernel 1: per-(b,c) plane mean. One block per plane, float4 loads. ----
// Normal (caching) loads on purpose: this pass is what populates L3 with x,
// and the fused pass re-reads it in reverse order to harvest those lines.
__global__ __launch_bounds__(256) void mean_kernel(const float4* __restrict__ x,
                                                   float* __restrict__ meanv) {
    const int plane = blockIdx.x;
    const float4* px = x + (size_t)plane * HW4;
    float s = 0.0f;
#pragma unroll
    for (int it = 0; it < HW4 / 256; ++it) {
        float4 v = px[threadIdx.x + it * 256];
        s += (v.x + v.y) + (v.z + v.w);
    }
    __shared__ float red[256];
    red[threadIdx.x] = s;
    __syncthreads();
    for (int off = 128; off > 0; off >>= 1) {
        if (threadIdx.x < off) red[threadIdx.x] += red[threadIdx.x + off];
        __syncthreads();
    }
    if (threadIdx.x == 0) meanv[plane] = red[0] * (1.0f / (float)HW);
}

// ---- Kernel 2 (fused): per-block redundant MLP + BN, then stream add. ----
// Block g handles planes [g*PPB, g*PPB+3] (all in one batch since 512 % 4 == 0).
// blockIdx is REVERSED so the planes that mean_kernel read last (still resident
// in the 256 MiB Infinity Cache) are re-read first. out is written with
// non-temporal stores so the write stream doesn't evict x from L2/L3.
__global__ __launch_bounds__(256) void fused_kernel(
    const float4* __restrict__ x,
    const float* __restrict__ meanv,
    const float* __restrict__ wg,      // [R_CH, C_CH]
    const float* __restrict__ wf,      // [C_CH, R_CH]
    const float* __restrict__ gamma,
    const float* __restrict__ beta,
    const float* __restrict__ mu,
    const float* __restrict__ var,
    float4* __restrict__ out) {
    const int g = (NBLK - 1) - (int)blockIdx.x;   // reversed plane order
    const int plane0 = g * PPB;
    const int b = plane0 >> 9;                    // /C_CH
    const int c0 = plane0 & (C_CH - 1);

    __shared__ float m[C_CH];
    __shared__ float part[256];
    __shared__ float t[R_CH];
    __shared__ float yv[PPB];

    const int tid = threadIdx.x;
    for (int c = tid; c < C_CH; c += 256) m[c] = meanv[b * C_CH + c];
    __syncthreads();

    // t[r] = relu6(dot(wg[r,:], m)) — each r computed by 2 threads (half rows each).
    {
        const int r = tid & (R_CH - 1);
        const int half = tid >> 7;                // 0 or 1
        const float4* w4 = (const float4*)(wg + (size_t)r * C_CH) + half * (C_CH / 8);
        const float* mh = m + half * (C_CH / 2);
        float a0 = 0.f, a1 = 0.f;
#pragma unroll 8
        for (int i = 0; i < C_CH / 8; ++i) {      // 64 float4 = 256 floats
            float4 v = w4[i];
            const int c = i * 4;
            a0 += v.x * mh[c + 0] + v.y * mh[c + 1];
            a1 += v.z * mh[c + 2] + v.w * mh[c + 3];
        }
        part[tid] = a0 + a1;
    }
    __syncthreads();
    if (tid < R_CH) t[tid] = relu6f(part[tid] + part[tid + R_CH]);
    __syncthreads();

    // y[c] = relu6(BN(dot(wf[c,:], t))) for the block's PPB channels.
    if (tid < PPB) {
        const int c = c0 + tid;
        const float4* w4 = (const float4*)(wf + (size_t)c * R_CH);
        float a0 = 0.f, a1 = 0.f;
#pragma unroll
        for (int i = 0; i < R_CH / 4; ++i) {
            float4 v = w4[i];
            const int r = i * 4;
            a0 += v.x * t[r + 0] + v.y * t[r + 1];
            a1 += v.z * t[r + 2] + v.w * t[r + 3];
        }
        const float s = a0 + a1;
        const float inv_std = 1.0f / sqrtf(var[c] + 1e-5f);
        yv[tid] = relu6f((s - mu[c]) * inv_std * gamma[c] + beta[c]);
    }
    __syncthreads();

    // Stream: out = x + y[plane], non-temporal stores (no L2/L3 allocate).
#pragma unroll
    for (int p = 0; p < PPB; ++p) {
        const float a = yv[p];
        const float4* px = x + (size_t)(plane0 + p) * HW4;
        floatx4* po = reinterpret_cast<floatx4*>(out + (size_t)(plane0 + p) * HW4);
#pragma unroll
        for (int it = 0; it < HW4 / 256; ++it) {
            const int i = tid + it * 256;
            float4 v = px[i];
            floatx4 w;
            w.x = v.x + a; w.y = v.y + a; w.z = v.z + a; w.w = v.w + a;
            __builtin_nontemporal_store(w, po + i);
        }
    }
}

extern "C" void kernel_launch(void* const* d_in, const int* in_sizes, int n_in,
                              void* d_out, int out_size, void* d_ws, size_t ws_size,
                              hipStream_t stream) {
    const float4* x4  = (const float4*)d_in[0];
    const float* wg   = (const float*)d_in[1];
    const float* wf   = (const float*)d_in[2];
    const float* gamma = (const float*)d_in[3];
    const float* beta  = (const float*)d_in[4];
    const float* mu    = (const float*)d_in[5];
    const float* var   = (const float*)d_in[6];

    float* meanv = (float*)d_ws;        // NPLANE floats
    float4* out  = (float4*)d_out;

    mean_kernel<<<NPLANE, 256, 0, stream>>>(x4, meanv);
    fused_kernel<<<NBLK, 256, 0, stream>>>(x4, meanv, wg, wf, gamma, beta,
                                           mu, var, out);
}